// Round 1
// baseline (929.229 us; speedup 1.0000x reference)
//
#include <hip/hip_runtime.h>
#include <hip/hip_bf16.h>

// GQA block, MI355X/gfx950.
// Pipeline:
//   prep:   x -> bf16; pack Wq|Wk|Wv transposed [n][c] bf16; Wo transposed [n][k] bf16
//   gemm<0>: xb @ WqkvT -> Qb [h][s][64] (x0.125, +bq), Kb [h][s][64] (+bk), VTb [h][64][s] (+bv)
//   attn:   per (head, 128 q rows): phase1 row max/sum (MFMA QK^T, shfl reduce),
//           phase2 recompute S, write normalized att (fp32, 537MB - the HBM floor),
//           P->LDS->A-frag, PV MFMA -> OAb [s][512] bf16
//   gemm<1>: OAb @ WobT + bo -> out fp32
// MFMA 16x16x32 bf16 layouts (verified per guide):
//   A: lane holds A[m=lane&15][k=quad*8+j]   B: B[k=quad*8+j][n=lane&15]
//   C/D: D[row=quad*4+reg][col=lane&15]

#define DIM   768
#define Sc    4096

typedef __bf16 bfrag __attribute__((ext_vector_type(8)));
typedef float  facc  __attribute__((ext_vector_type(4)));

#define MFMA_BF16(a,b,c) __builtin_amdgcn_mfma_f32_16x16x32_bf16((a),(b),(c),0,0,0)

// ---------------------------------------------------------------- prep
__global__ __launch_bounds__(256) void prep_kernel(
    const float* __restrict__ x,  const float* __restrict__ Wq,
    const float* __restrict__ Wk, const float* __restrict__ Wv,
    const float* __restrict__ Wo,
    __bf16* __restrict__ xb, __bf16* __restrict__ WqkvT, __bf16* __restrict__ WobT)
{
  int i = blockIdx.x * 256 + threadIdx.x;
  const int NX = Sc * DIM;      // 3145728
  const int NW = DIM * DIM;     // 589824
  if (i < NX) { xb[i] = (__bf16)x[i]; return; }
  i -= NX;
  if (i < NW) {                 // WqkvT[n][c]
    int n = i / DIM, c = i - n * DIM;
    float v;
    if (n < 512)      v = Wq[c * 512 + n];
    else if (n < 640) v = Wk[c * 128 + (n - 512)];
    else              v = Wv[c * 128 + (n - 640)];
    WqkvT[i] = (__bf16)v;
    return;
  }
  i -= NW;
  {                             // WobT[n][k], n<768, k<512
    int n = i / 512, k = i - n * 512;
    WobT[i] = (__bf16)Wo[k * DIM + n];
  }
}

// ---------------------------------------------------------------- gemm
// C[M=4096, N=768] = A[M,Kd] @ BT[N,Kd]^T, 128x64 block tile, 4 waves x (32r x 64c), BK=64.
// MODE 0: QKV epilogue (scatter to Qb/Kb/VTb, bias, Q scale 0.125). MODE 1: fp32 out + b0.
template<int MODE>
__global__ __launch_bounds__(256) void gemm_kernel(
    const __bf16* __restrict__ A, const __bf16* __restrict__ BT, int Kd,
    const float* __restrict__ b0, const float* __restrict__ b1, const float* __restrict__ b2,
    __bf16* __restrict__ Qb, __bf16* __restrict__ Kb, __bf16* __restrict__ VTb,
    float* __restrict__ Cout)
{
  const int tid  = threadIdx.x;
  const int w    = tid >> 6;
  const int lane = tid & 63;
  const int i16  = lane & 15;
  const int quad = lane >> 4;
  const int n0   = blockIdx.x * 64;
  const int m0   = blockIdx.y * 128;

  __shared__ __attribute__((aligned(16))) __bf16 Al[128 * 72];  // rows padded +8 (16B align kept)
  __shared__ __attribute__((aligned(16))) __bf16 Bl[64 * 72];

  facc acc[2][4];
#pragma unroll
  for (int mt = 0; mt < 2; ++mt)
#pragma unroll
    for (int nt = 0; nt < 4; ++nt)
      acc[mt][nt] = (facc){0.f, 0.f, 0.f, 0.f};

  const int nkt = Kd >> 6;
  for (int kt = 0; kt < nkt; ++kt) {
#pragma unroll
    for (int it = 0; it < 4; ++it) {       // A tile: 128 rows x 64k = 1024 x 16B chunks
      int idx = tid + it * 256;
      int r = idx >> 3, ch = idx & 7;
      *(uint4*)&Al[r * 72 + ch * 8] =
          *(const uint4*)(A + (size_t)(m0 + r) * Kd + (kt * 64 + ch * 8));
    }
#pragma unroll
    for (int it = 0; it < 2; ++it) {       // BT tile: 64 n-rows x 64k
      int idx = tid + it * 256;
      int r = idx >> 3, ch = idx & 7;
      *(uint4*)&Bl[r * 72 + ch * 8] =
          *(const uint4*)(BT + (size_t)(n0 + r) * Kd + (kt * 64 + ch * 8));
    }
    __syncthreads();
#pragma unroll
    for (int ks = 0; ks < 2; ++ks) {
      bfrag a0 = *(const bfrag*)&Al[(w * 32 + i16) * 72 + ks * 32 + quad * 8];
      bfrag a1 = *(const bfrag*)&Al[(w * 32 + 16 + i16) * 72 + ks * 32 + quad * 8];
#pragma unroll
      for (int nt = 0; nt < 4; ++nt) {
        bfrag b = *(const bfrag*)&Bl[(nt * 16 + i16) * 72 + ks * 32 + quad * 8];
        acc[0][nt] = MFMA_BF16(a0, b, acc[0][nt]);
        acc[1][nt] = MFMA_BF16(a1, b, acc[1][nt]);
      }
    }
    __syncthreads();
  }

#pragma unroll
  for (int mt = 0; mt < 2; ++mt)
#pragma unroll
    for (int nt = 0; nt < 4; ++nt) {
      const int n = n0 + nt * 16 + i16;
      const int rbase = m0 + w * 32 + mt * 16 + quad * 4;
      if (MODE == 0) {
        float bias;
        if (n < 512)      bias = b0[n];
        else if (n < 640) bias = b1[n - 512];
        else              bias = b2[n - 640];
#pragma unroll
        for (int reg = 0; reg < 4; ++reg) {
          float v = acc[mt][nt][reg] + bias;
          int row = rbase + reg;
          if (n < 512) {                    // Q: fold 1/sqrt(64)
            int hh = n >> 6, d = n & 63;
            Qb[((size_t)hh * Sc + row) * 64 + d] = (__bf16)(v * 0.125f);
          } else if (n < 640) {             // K
            int hh = (n - 512) >> 6, d = n & 63;
            Kb[((size_t)hh * Sc + row) * 64 + d] = (__bf16)v;
          } else {                          // V stored transposed: VT[h][d][s]
            int hh = (n - 640) >> 6, d = n & 63;
            VTb[(size_t)hh * 64 * Sc + (size_t)d * Sc + row] = (__bf16)v;
          }
        }
      } else {
        float bias = b0[n];
#pragma unroll
        for (int reg = 0; reg < 4; ++reg)
          Cout[(size_t)(rbase + reg) * DIM + n] = acc[mt][nt][reg] + bias;
      }
    }
}

// ---------------------------------------------------------------- attention
// grid (32 qblocks, 8 heads), 256 thr = 4 waves, wave = 32 q-rows, k-tile = 64.
__global__ __launch_bounds__(256) void attn_kernel(
    const __bf16* __restrict__ Qb, const __bf16* __restrict__ Kb,
    const __bf16* __restrict__ VTb,
    float* __restrict__ att, __bf16* __restrict__ OAb)
{
  const int tid  = threadIdx.x;
  const int w    = tid >> 6;
  const int lane = tid & 63;
  const int i16  = lane & 15;
  const int quad = lane >> 4;
  const int h    = blockIdx.y;
  const int kvh  = h >> 2;          // n_rep = 4
  const int q0   = blockIdx.x * 128;

  __shared__ __attribute__((aligned(16))) __bf16 Kl[64 * 72];
  __shared__ __attribute__((aligned(16))) __bf16 Vl[64 * 72];   // V^T tile: [d][kc]
  __shared__ __attribute__((aligned(16))) __bf16 Pl[128 * 72];  // P, per-wave band

  // Q A-fragments live in registers for the whole kernel (already scaled by 0.125)
  bfrag qf[2][2];
#pragma unroll
  for (int mt = 0; mt < 2; ++mt)
#pragma unroll
    for (int ks = 0; ks < 2; ++ks)
      qf[mt][ks] = *(const bfrag*)(Qb +
          ((size_t)h * Sc + q0 + w * 32 + mt * 16 + i16) * 64 + ks * 32 + quad * 8);

  float mrun[2][4], lrun[2][4];
#pragma unroll
  for (int mt = 0; mt < 2; ++mt)
#pragma unroll
    for (int r = 0; r < 4; ++r) { mrun[mt][r] = -1e30f; lrun[mt][r] = 0.f; }

  const __bf16* Kbase = Kb  + (size_t)kvh * Sc * 64;
  const __bf16* Vbase = VTb + (size_t)kvh * 64 * Sc;

  // ---------------- phase 1: row max / sum ----------------
  for (int kt = 0; kt < 64; ++kt) {
#pragma unroll
    for (int it = 0; it < 2; ++it) {
      int idx = tid + it * 256; int r = idx >> 3, ch = idx & 7;
      *(uint4*)&Kl[r * 72 + ch * 8] =
          *(const uint4*)(Kbase + (size_t)(kt * 64 + r) * 64 + ch * 8);
    }
    __syncthreads();
    facc s[2][4];
#pragma unroll
    for (int mt = 0; mt < 2; ++mt)
#pragma unroll
      for (int nt = 0; nt < 4; ++nt)
        s[mt][nt] = (facc){0.f, 0.f, 0.f, 0.f};
#pragma unroll
    for (int ks = 0; ks < 2; ++ks)
#pragma unroll
      for (int mt = 0; mt < 2; ++mt) {
        bfrag a = qf[mt][ks];
#pragma unroll
        for (int nt = 0; nt < 4; ++nt) {
          bfrag b = *(const bfrag*)&Kl[(nt * 16 + i16) * 72 + ks * 32 + quad * 8];
          s[mt][nt] = MFMA_BF16(a, b, s[mt][nt]);
        }
      }
#pragma unroll
    for (int mt = 0; mt < 2; ++mt)
#pragma unroll
      for (int r = 0; r < 4; ++r) {
        float tm = fmaxf(fmaxf(s[mt][0][r], s[mt][1][r]), fmaxf(s[mt][2][r], s[mt][3][r]));
        tm = fmaxf(tm, __shfl_xor(tm, 1));
        tm = fmaxf(tm, __shfl_xor(tm, 2));
        tm = fmaxf(tm, __shfl_xor(tm, 4));
        tm = fmaxf(tm, __shfl_xor(tm, 8));
        float mnew = fmaxf(mrun[mt][r], tm);
        float ts = __expf(s[mt][0][r] - mnew) + __expf(s[mt][1][r] - mnew)
                 + __expf(s[mt][2][r] - mnew) + __expf(s[mt][3][r] - mnew);
        ts += __shfl_xor(ts, 1);
        ts += __shfl_xor(ts, 2);
        ts += __shfl_xor(ts, 4);
        ts += __shfl_xor(ts, 8);
        lrun[mt][r] = lrun[mt][r] * __expf(mrun[mt][r] - mnew) + ts;
        mrun[mt][r] = mnew;
      }
    __syncthreads();
  }

  float linv[2][4];
#pragma unroll
  for (int mt = 0; mt < 2; ++mt)
#pragma unroll
    for (int r = 0; r < 4; ++r) linv[mt][r] = 1.f / lrun[mt][r];

  facc oacc[2][4];
#pragma unroll
  for (int mt = 0; mt < 2; ++mt)
#pragma unroll
    for (int nt = 0; nt < 4; ++nt)
      oacc[mt][nt] = (facc){0.f, 0.f, 0.f, 0.f};

  float* attb = att + (size_t)h * Sc * Sc;

  // ---------------- phase 2: recompute S, write att, PV ----------------
  for (int kt = 0; kt < 64; ++kt) {
#pragma unroll
    for (int it = 0; it < 2; ++it) {
      int idx = tid + it * 256; int r = idx >> 3, ch = idx & 7;
      *(uint4*)&Kl[r * 72 + ch * 8] =
          *(const uint4*)(Kbase + (size_t)(kt * 64 + r) * 64 + ch * 8);
    }
#pragma unroll
    for (int it = 0; it < 2; ++it) {
      int idx = tid + it * 256; int r = idx >> 3, ch = idx & 7;
      *(uint4*)&Vl[r * 72 + ch * 8] =
          *(const uint4*)(Vbase + (size_t)r * Sc + kt * 64 + ch * 8);
    }
    __syncthreads();
    facc s[2][4];
#pragma unroll
    for (int mt = 0; mt < 2; ++mt)
#pragma unroll
      for (int nt = 0; nt < 4; ++nt)
        s[mt][nt] = (facc){0.f, 0.f, 0.f, 0.f};
#pragma unroll
    for (int ks = 0; ks < 2; ++ks)
#pragma unroll
      for (int mt = 0; mt < 2; ++mt) {
        bfrag a = qf[mt][ks];
#pragma unroll
        for (int nt = 0; nt < 4; ++nt) {
          bfrag b = *(const bfrag*)&Kl[(nt * 16 + i16) * 72 + ks * 32 + quad * 8];
          s[mt][nt] = MFMA_BF16(a, b, s[mt][nt]);
        }
      }
    // normalized probabilities: global att store (fp32) + LDS (bf16, own-wave band)
#pragma unroll
    for (int mt = 0; mt < 2; ++mt)
#pragma unroll
      for (int nt = 0; nt < 4; ++nt)
#pragma unroll
        for (int r = 0; r < 4; ++r) {
          float p = __expf(s[mt][nt][r] - mrun[mt][r]) * linv[mt][r];
          int row = q0 + w * 32 + mt * 16 + quad * 4 + r;
          attb[(size_t)row * Sc + kt * 64 + nt * 16 + i16] = p;
          Pl[(w * 32 + mt * 16 + quad * 4 + r) * 72 + nt * 16 + i16] = (__bf16)p;
        }
    // PV: P (A-layout, same wave wrote it -> no barrier needed) x V^T tile (B-layout)
#pragma unroll
    for (int ks = 0; ks < 2; ++ks)
#pragma unroll
      for (int mt = 0; mt < 2; ++mt) {
        bfrag pa = *(const bfrag*)&Pl[(w * 32 + mt * 16 + i16) * 72 + ks * 32 + quad * 8];
#pragma unroll
        for (int nt = 0; nt < 4; ++nt) {
          bfrag bvv = *(const bfrag*)&Vl[(nt * 16 + i16) * 72 + ks * 32 + quad * 8];
          oacc[mt][nt] = MFMA_BF16(pa, bvv, oacc[mt][nt]);
        }
      }
    __syncthreads();
  }

#pragma unroll
  for (int mt = 0; mt < 2; ++mt)
#pragma unroll
    for (int nt = 0; nt < 4; ++nt)
#pragma unroll
      for (int r = 0; r < 4; ++r) {
        int row = q0 + w * 32 + mt * 16 + quad * 4 + r;
        OAb[(size_t)row * 512 + h * 64 + nt * 16 + i16] = (__bf16)oacc[mt][nt][r];
      }
}

// ---------------------------------------------------------------- launch
extern "C" void kernel_launch(void* const* d_in, const int* in_sizes, int n_in,
                              void* d_out, int out_size, void* d_ws, size_t ws_size,
                              hipStream_t stream) {
  const float* x  = (const float*)d_in[0];
  const float* Wq = (const float*)d_in[1];
  const float* bq = (const float*)d_in[2];
  const float* Wk = (const float*)d_in[3];
  const float* bk = (const float*)d_in[4];
  const float* Wv = (const float*)d_in[5];
  const float* bv = (const float*)d_in[6];
  const float* Wo = (const float*)d_in[7];
  const float* bo = (const float*)d_in[8];

  float* out = (float*)d_out;
  float* att = out + (size_t)Sc * DIM;   // outputs concatenated: out then att

  char* ws = (char*)d_ws;
  size_t off = 0;
  __bf16* xb    = (__bf16*)(ws + off); off += (size_t)Sc * DIM * 2;        // 6291456
  __bf16* WqkvT = (__bf16*)(ws + off); off += (size_t)DIM * DIM * 2;       // 1179648
  __bf16* WobT  = (__bf16*)(ws + off); off += (size_t)DIM * 512 * 2;       // 786432
  __bf16* Qb    = (__bf16*)(ws + off); off += (size_t)8 * Sc * 64 * 2;     // 4194304
  __bf16* Kb    = (__bf16*)(ws + off); off += (size_t)2 * Sc * 64 * 2;     // 1048576
  __bf16* VTb   = (__bf16*)(ws + off); off += (size_t)2 * 64 * Sc * 2;     // 1048576
  __bf16* OAb   = (__bf16*)(ws + off); off += (size_t)Sc * 512 * 2;        // 4194304
  // total ~18.7 MB of ws

  prep_kernel<<<16128, 256, 0, stream>>>(x, Wq, Wk, Wv, Wo, xb, WqkvT, WobT);
  gemm_kernel<0><<<dim3(12, 32), 256, 0, stream>>>(xb, WqkvT, 768, bq, bk, bv,
                                                   Qb, Kb, VTb, nullptr);
  attn_kernel<<<dim3(32, 8), 256, 0, stream>>>(Qb, Kb, VTb, att, OAb);
  gemm_kernel<1><<<dim3(12, 32), 256, 0, stream>>>(OAb, WobT, 512, bo, nullptr, nullptr,
                                                   nullptr, nullptr, nullptr, out);
}

// Round 2
// 877.131 us; speedup vs baseline: 1.0594x; 1.0594x over previous
//
#include <hip/hip_runtime.h>
#include <hip/hip_bf16.h>

// GQA block, MI355X/gfx950. Round 2: occupancy-first attention.
//   prep:   x -> bf16; pack Wq|Wk|Wv transposed [n][c] bf16; Wo transposed [n][k] bf16
//   gemm<0>: xb @ WqkvT -> Qb [h][s][64] (x0.125, +bq), Kb [h][s][64] (+bk), VTb [h][64][s] (+bv)
//   attn v2: grid (256 q-tiles of 16 rows, 8 heads) = 2048 blocks. 4 waves/block each
//            own a 1024-key quarter; partial online softmax stats combined once via LDS;
//            phase2 recomputes S, writes normalized att (fp32 dwordx4 via LDS round-trip
//            that doubles as the P C-layout -> A-layout transform), PV partials reduced
//            once at the end. ZERO barriers in the K-loops; K/V read direct from global
//            (2 MB per kv-head -> L2-resident).
//   gemm<1>: OAb @ WobT + bo -> out fp32
// MFMA 16x16x32 bf16 layouts:
//   A: lane holds A[m=lane&15][k=quad*8+j]   B: B[k=quad*8+j][n=lane&15]
//   C/D: D[row=quad*4+reg][col=lane&15]

#define DIM   768
#define Sc    4096

typedef __bf16 bfrag __attribute__((ext_vector_type(8)));
typedef float  facc  __attribute__((ext_vector_type(4)));

#define MFMA_BF16(a,b,c) __builtin_amdgcn_mfma_f32_16x16x32_bf16((a),(b),(c),0,0,0)

// ---------------------------------------------------------------- prep
__global__ __launch_bounds__(256) void prep_kernel(
    const float* __restrict__ x,  const float* __restrict__ Wq,
    const float* __restrict__ Wk, const float* __restrict__ Wv,
    const float* __restrict__ Wo,
    __bf16* __restrict__ xb, __bf16* __restrict__ WqkvT, __bf16* __restrict__ WobT)
{
  int i = blockIdx.x * 256 + threadIdx.x;
  const int NX = Sc * DIM;      // 3145728
  const int NW = DIM * DIM;     // 589824
  if (i < NX) { xb[i] = (__bf16)x[i]; return; }
  i -= NX;
  if (i < NW) {                 // WqkvT[n][c]
    int n = i / DIM, c = i - n * DIM;
    float v;
    if (n < 512)      v = Wq[c * 512 + n];
    else if (n < 640) v = Wk[c * 128 + (n - 512)];
    else              v = Wv[c * 128 + (n - 640)];
    WqkvT[i] = (__bf16)v;
    return;
  }
  i -= NW;
  {                             // WobT[n][k], n<768, k<512
    int n = i / 512, k = i - n * 512;
    WobT[i] = (__bf16)Wo[k * DIM + n];
  }
}

// ---------------------------------------------------------------- gemm
// C[M=4096, N] = A[M,Kd] @ BT[N,Kd]^T. 64x64 block tile, 4 waves x (16r x 64c), BK=64.
// MODE 0: QKV epilogue (scatter to Qb/Kb/VTb, bias, Q scale 0.125). MODE 1: fp32 out + b0.
template<int MODE>
__global__ __launch_bounds__(256) void gemm_kernel(
    const __bf16* __restrict__ A, const __bf16* __restrict__ BT, int Kd,
    const float* __restrict__ b0, const float* __restrict__ b1, const float* __restrict__ b2,
    __bf16* __restrict__ Qb, __bf16* __restrict__ Kb, __bf16* __restrict__ VTb,
    float* __restrict__ Cout)
{
  const int tid  = threadIdx.x;
  const int w    = tid >> 6;
  const int lane = tid & 63;
  const int i16  = lane & 15;
  const int quad = lane >> 4;
  const int n0   = blockIdx.x * 64;
  const int m0   = blockIdx.y * 64;

  __shared__ __attribute__((aligned(16))) __bf16 Al[64 * 72];
  __shared__ __attribute__((aligned(16))) __bf16 Bl[64 * 72];

  facc acc[4];
#pragma unroll
  for (int nt = 0; nt < 4; ++nt) acc[nt] = (facc){0.f, 0.f, 0.f, 0.f};

  const int nkt = Kd >> 6;
  for (int kt = 0; kt < nkt; ++kt) {
#pragma unroll
    for (int it = 0; it < 2; ++it) {       // A tile: 64 rows x 64k = 512 x 16B chunks
      int idx = tid + it * 256;
      int r = idx >> 3, ch = idx & 7;
      *(uint4*)&Al[r * 72 + ch * 8] =
          *(const uint4*)(A + (size_t)(m0 + r) * Kd + (kt * 64 + ch * 8));
    }
#pragma unroll
    for (int it = 0; it < 2; ++it) {       // BT tile
      int idx = tid + it * 256;
      int r = idx >> 3, ch = idx & 7;
      *(uint4*)&Bl[r * 72 + ch * 8] =
          *(const uint4*)(BT + (size_t)(n0 + r) * Kd + (kt * 64 + ch * 8));
    }
    __syncthreads();
#pragma unroll
    for (int ks = 0; ks < 2; ++ks) {
      bfrag a = *(const bfrag*)&Al[(w * 16 + i16) * 72 + ks * 32 + quad * 8];
#pragma unroll
      for (int nt = 0; nt < 4; ++nt) {
        bfrag b = *(const bfrag*)&Bl[(nt * 16 + i16) * 72 + ks * 32 + quad * 8];
        acc[nt] = MFMA_BF16(a, b, acc[nt]);
      }
    }
    __syncthreads();
  }

#pragma unroll
  for (int nt = 0; nt < 4; ++nt) {
    const int n = n0 + nt * 16 + i16;
    const int rbase = m0 + w * 16 + quad * 4;
    if (MODE == 0) {
      float bias;
      if (n < 512)      bias = b0[n];
      else if (n < 640) bias = b1[n - 512];
      else              bias = b2[n - 640];
#pragma unroll
      for (int reg = 0; reg < 4; ++reg) {
        float v = acc[nt][reg] + bias;
        int row = rbase + reg;
        if (n < 512) {                    // Q: fold 1/sqrt(64)
          int hh = n >> 6, d = n & 63;
          Qb[((size_t)hh * Sc + row) * 64 + d] = (__bf16)(v * 0.125f);
        } else if (n < 640) {             // K
          int hh = (n - 512) >> 6, d = n & 63;
          Kb[((size_t)hh * Sc + row) * 64 + d] = (__bf16)v;
        } else {                          // V stored transposed: VT[h][d][s]
          int hh = (n - 640) >> 6, d = n & 63;
          VTb[(size_t)hh * 64 * Sc + (size_t)d * Sc + row] = (__bf16)v;
        }
      }
    } else {
      float bias = b0[n];
#pragma unroll
      for (int reg = 0; reg < 4; ++reg)
        Cout[(size_t)(rbase + reg) * DIM + n] = acc[nt][reg] + bias;
    }
  }
}

// ---------------------------------------------------------------- attention v2
// grid (Sc/16 = 256, 8 heads), 256 thr = 4 waves. Block = 16 q-rows; wave w owns
// keys [w*1024, (w+1)*1024). No barriers inside the K loops.
#define PFSTRIDE 68            // fp32 row stride (64 + 4 pad)
#define PFWAVE   (16 * PFSTRIDE + 4)   // 1092: per-wave region, +4 breaks w-stride conflicts

__global__ __launch_bounds__(256, 6) void attn_kernel(
    const __bf16* __restrict__ Qb, const __bf16* __restrict__ Kb,
    const __bf16* __restrict__ VTb,
    float* __restrict__ att, __bf16* __restrict__ OAb)
{
  const int tid  = threadIdx.x;
  const int w    = tid >> 6;
  const int lane = tid & 63;
  const int i16  = lane & 15;
  const int quad = lane >> 4;
  const int h    = blockIdx.y;
  const int kvh  = h >> 2;          // n_rep = 4
  const int q0   = blockIdx.x * 16;

  __shared__ __attribute__((aligned(16))) float Pf[4 * PFWAVE];  // ~17.5 KB
  __shared__ float SM[4][16], SL[4][16];

  const __bf16* Kbase = Kb  + (size_t)kvh * Sc * 64;
  const __bf16* Vbase = VTb + (size_t)kvh * 64 * Sc;

  // Q A-fragments (already scaled by 0.125), 16 rows
  bfrag qf[2];
#pragma unroll
  for (int ks = 0; ks < 2; ++ks)
    qf[ks] = *(const bfrag*)(Qb + ((size_t)h * Sc + q0 + i16) * 64 + ks * 32 + quad * 8);

  float mrun[4], lrun[4];
#pragma unroll
  for (int r = 0; r < 4; ++r) { mrun[r] = -1e30f; lrun[r] = 0.f; }

  const int key0 = w * 1024;

  // ---------------- phase 1: partial row max / sum over this wave's quarter ----
  for (int kt = 0; kt < 16; ++kt) {
    const int kb0 = key0 + kt * 64;
    facc s[4];
#pragma unroll
    for (int nt = 0; nt < 4; ++nt) s[nt] = (facc){0.f, 0.f, 0.f, 0.f};
#pragma unroll
    for (int ks = 0; ks < 2; ++ks)
#pragma unroll
      for (int nt = 0; nt < 4; ++nt) {
        bfrag kf = *(const bfrag*)(Kbase + (size_t)(kb0 + nt * 16 + i16) * 64 + ks * 32 + quad * 8);
        s[nt] = MFMA_BF16(qf[ks], kf, s[nt]);
      }
#pragma unroll
    for (int r = 0; r < 4; ++r) {
      float tm = fmaxf(fmaxf(s[0][r], s[1][r]), fmaxf(s[2][r], s[3][r]));
      tm = fmaxf(tm, __shfl_xor(tm, 1));
      tm = fmaxf(tm, __shfl_xor(tm, 2));
      tm = fmaxf(tm, __shfl_xor(tm, 4));
      tm = fmaxf(tm, __shfl_xor(tm, 8));
      float mnew = fmaxf(mrun[r], tm);
      float ts = __expf(s[0][r] - mnew) + __expf(s[1][r] - mnew)
               + __expf(s[2][r] - mnew) + __expf(s[3][r] - mnew);
      ts += __shfl_xor(ts, 1);
      ts += __shfl_xor(ts, 2);
      ts += __shfl_xor(ts, 4);
      ts += __shfl_xor(ts, 8);
      lrun[r] = lrun[r] * __expf(mrun[r] - mnew) + ts;
      mrun[r] = mnew;
    }
  }

  // ---------------- combine stats across the 4 waves ----------------
  if (i16 == 0) {
#pragma unroll
    for (int r = 0; r < 4; ++r) { SM[w][quad * 4 + r] = mrun[r]; SL[w][quad * 4 + r] = lrun[r]; }
  }
  __syncthreads();
  float mglob[4], linv[4];
#pragma unroll
  for (int r = 0; r < 4; ++r) {
    const int rr = quad * 4 + r;
    float m0v = SM[0][rr], m1v = SM[1][rr], m2v = SM[2][rr], m3v = SM[3][rr];
    float mg = fmaxf(fmaxf(m0v, m1v), fmaxf(m2v, m3v));
    float lg = SL[0][rr] * __expf(m0v - mg) + SL[1][rr] * __expf(m1v - mg)
             + SL[2][rr] * __expf(m2v - mg) + SL[3][rr] * __expf(m3v - mg);
    mglob[r] = mg;
    linv[r]  = 1.f / lg;
  }

  facc oacc[4];
#pragma unroll
  for (int nt = 0; nt < 4; ++nt) oacc[nt] = (facc){0.f, 0.f, 0.f, 0.f};

  float* attb = att + (size_t)h * Sc * Sc;
  float* Pw   = Pf + w * PFWAVE;

  // ---------------- phase 2: recompute S, write att, PV ----------------
  for (int kt = 0; kt < 16; ++kt) {
    const int kb0 = key0 + kt * 64;
    facc s[4];
#pragma unroll
    for (int nt = 0; nt < 4; ++nt) s[nt] = (facc){0.f, 0.f, 0.f, 0.f};
#pragma unroll
    for (int ks = 0; ks < 2; ++ks)
#pragma unroll
      for (int nt = 0; nt < 4; ++nt) {
        bfrag kf = *(const bfrag*)(Kbase + (size_t)(kb0 + nt * 16 + i16) * 64 + ks * 32 + quad * 8);
        s[nt] = MFMA_BF16(qf[ks], kf, s[nt]);
      }
    // normalized probabilities -> per-wave fp32 LDS tile (C-layout writes)
#pragma unroll
    for (int nt = 0; nt < 4; ++nt)
#pragma unroll
      for (int r = 0; r < 4; ++r)
        Pw[(quad * 4 + r) * PFSTRIDE + nt * 16 + i16] =
            __expf(s[nt][r] - mglob[r]) * linv[r];
    // A-layout fragments out of the same tile (same wave: no barrier)
    bfrag pa[2];
#pragma unroll
    for (int ks = 0; ks < 2; ++ks) {
      facc p0 = *(const facc*)&Pw[i16 * PFSTRIDE + ks * 32 + quad * 8];
      facc p1 = *(const facc*)&Pw[i16 * PFSTRIDE + ks * 32 + quad * 8 + 4];
      bfrag t;
      t[0] = (__bf16)p0[0]; t[1] = (__bf16)p0[1]; t[2] = (__bf16)p0[2]; t[3] = (__bf16)p0[3];
      t[4] = (__bf16)p1[0]; t[5] = (__bf16)p1[1]; t[6] = (__bf16)p1[2]; t[7] = (__bf16)p1[3];
      pa[ks] = t;
    }
    // PV with V^T fragments direct from global (L2-resident)
#pragma unroll
    for (int ks = 0; ks < 2; ++ks)
#pragma unroll
      for (int nt = 0; nt < 4; ++nt) {
        bfrag vf = *(const bfrag*)(Vbase + (size_t)(nt * 16 + i16) * Sc + kb0 + ks * 32 + quad * 8);
        oacc[nt] = MFMA_BF16(pa[ks], vf, oacc[nt]);
      }
    // coalesced att store: 4 x dwordx4, 256B per quad-row
#pragma unroll
    for (int it = 0; it < 4; ++it) {
      int flat = it * 64 + lane;
      int row = flat >> 4, c4 = flat & 15;
      facc v = *(const facc*)&Pw[row * PFSTRIDE + c4 * 4];
      *(facc*)&attb[(size_t)(q0 + row) * Sc + kb0 + c4 * 4] = v;
    }
  }

  // ---------------- reduce O partials across waves (reuse Pf) ----------------
#pragma unroll
  for (int nt = 0; nt < 4; ++nt)
#pragma unroll
    for (int r = 0; r < 4; ++r)
      Pw[(quad * 4 + r) * PFSTRIDE + nt * 16 + i16] = oacc[nt][r];
  __syncthreads();
#pragma unroll
  for (int it = 0; it < 4; ++it) {
    int e = it * 256 + tid;
    int row = e >> 6, d = e & 63;
    float sum = Pf[0 * PFWAVE + row * PFSTRIDE + d] + Pf[1 * PFWAVE + row * PFSTRIDE + d]
              + Pf[2 * PFWAVE + row * PFSTRIDE + d] + Pf[3 * PFWAVE + row * PFSTRIDE + d];
    OAb[(size_t)(q0 + row) * 512 + h * 64 + d] = (__bf16)sum;
  }
}

// ---------------------------------------------------------------- launch
extern "C" void kernel_launch(void* const* d_in, const int* in_sizes, int n_in,
                              void* d_out, int out_size, void* d_ws, size_t ws_size,
                              hipStream_t stream) {
  const float* x  = (const float*)d_in[0];
  const float* Wq = (const float*)d_in[1];
  const float* bq = (const float*)d_in[2];
  const float* Wk = (const float*)d_in[3];
  const float* bk = (const float*)d_in[4];
  const float* Wv = (const float*)d_in[5];
  const float* bv = (const float*)d_in[6];
  const float* Wo = (const float*)d_in[7];
  const float* bo = (const float*)d_in[8];

  float* out = (float*)d_out;
  float* att = out + (size_t)Sc * DIM;   // outputs concatenated: out then att

  char* ws = (char*)d_ws;
  size_t off = 0;
  __bf16* xb    = (__bf16*)(ws + off); off += (size_t)Sc * DIM * 2;
  __bf16* WqkvT = (__bf16*)(ws + off); off += (size_t)DIM * DIM * 2;
  __bf16* WobT  = (__bf16*)(ws + off); off += (size_t)DIM * 512 * 2;
  __bf16* Qb    = (__bf16*)(ws + off); off += (size_t)8 * Sc * 64 * 2;
  __bf16* Kb    = (__bf16*)(ws + off); off += (size_t)2 * Sc * 64 * 2;
  __bf16* VTb   = (__bf16*)(ws + off); off += (size_t)2 * 64 * Sc * 2;
  __bf16* OAb   = (__bf16*)(ws + off); off += (size_t)Sc * 512 * 2;

  prep_kernel<<<16128, 256, 0, stream>>>(x, Wq, Wk, Wv, Wo, xb, WqkvT, WobT);
  gemm_kernel<0><<<dim3(12, 64), 256, 0, stream>>>(xb, WqkvT, 768, bq, bk, bv,
                                                   Qb, Kb, VTb, nullptr);
  attn_kernel<<<dim3(256, 8), 256, 0, stream>>>(Qb, Kb, VTb, att, OAb);
  gemm_kernel<1><<<dim3(12, 64), 256, 0, stream>>>(OAb, WobT, 512, bo, nullptr, nullptr,
                                                   nullptr, nullptr, nullptr, out);
}